// Round 2
// baseline (93.755 us; speedup 1.0000x reference)
//
#include <hip/hip_runtime.h>

// Upsample1d (linear kernel, reflect pad), stride-2 transposed depthwise FIR.
//   out[2m]   = 0.25*h[m-1] + 0.75*h[m]   (h[-1] := h[1])
//   out[2m+1] = 0.75*h[m]   + 0.25*h[m+1] (h[L]  := h[L-2])
// Taps hard-coded: _LINEAR_KERNEL*2 = [0.25, 0.75, 0.75, 0.25] (fixed by setup).
//
// One thread per OUTPUT float4 (positions 4t..4t+3) -> needs h[2t-1..2t+2].
// Load float2 (h[2t],h[2t+1]) (8B/lane, contiguous across wave); neighbors
// come from adjacent lanes via shfl; only wave-edge lanes issue a scalar load.
// Single 16B store per lane, contiguous across the wave -> every load and
// store instruction is perfectly coalesced (fixes the 32B-stride gapped
// stores of the previous version).

__global__ __launch_bounds__(256) void upsample1d_kernel(
    const float* __restrict__ h, float* __restrict__ out, int L) {
    const int tpr = L >> 1;               // threads per row = 2L/4 = L/2
    const int row = blockIdx.y;
    const int t = blockIdx.x * blockDim.x + threadIdx.x;   // 0..tpr-1

    const float* __restrict__ hr = h + (long long)row * L;
    float* __restrict__ orow = out + (long long)row * 2 * L;

    const int i0 = t << 1;                // input index of h[2t]
    const float2 f2 = *reinterpret_cast<const float2*>(hr + i0);

    // stencil neighbors from adjacent lanes
    float left  = __shfl_up(f2.y, 1);     // h[2t-1]
    float right = __shfl_down(f2.x, 1);   // h[2t+2]

    const int lane = threadIdx.x & 63;
    if (lane == 0)  left  = (t > 0)       ? hr[i0 - 1] : f2.y;  // reflect h[-1]=h[1]
    if (lane == 63) right = (t < tpr - 1) ? hr[i0 + 2] : f2.x;  // reflect h[L]=h[L-2]

    float4 o;
    o.x = 0.25f * left + 0.75f * f2.x;    // out[4t]   = k3*h[2t-1] + k1*h[2t]
    o.y = 0.75f * f2.x + 0.25f * f2.y;    // out[4t+1] = k2*h[2t]   + k0*h[2t+1]
    o.z = 0.25f * f2.x + 0.75f * f2.y;    // out[4t+2] = k3*h[2t]   + k1*h[2t+1]
    o.w = 0.75f * f2.y + 0.25f * right;   // out[4t+3] = k2*h[2t+1] + k0*h[2t+2]

    *reinterpret_cast<float4*>(orow + (i0 << 1)) = o;
}

extern "C" void kernel_launch(void* const* d_in, const int* in_sizes, int n_in,
                              void* d_out, int out_size, void* d_ws, size_t ws_size,
                              hipStream_t stream) {
    const float* h = (const float*)d_in[0];
    float* out = (float*)d_out;

    const int L = 8192;                    // fixed by the reference problem
    const int nrows = in_sizes[0] / L;     // B*C = 4096
    const int tpr = L / 2;                 // 4096 threads per row
    const int block = 256;
    dim3 grid(tpr / block, nrows);         // (16, 4096)

    upsample1d_kernel<<<grid, block, 0, stream>>>(h, out, L);
}